// Round 4
// baseline (185.320 us; speedup 1.0000x reference)
//
#include <hip/hip_runtime.h>
#include <math.h>

// S4 DPLR kernel + batched causal convolution via custom packed-real FFTs.
//
//  A) s4_khat_kernel : Y[l] = Hermitian-forced K_hat (fp64, stable Cauchy form,
//       c*inv = 2/(20(1-w) - (1+w)Lambda)); also cot table T[d].  [verified r3]
//  B) s4_tabs_kernel : 512 WGs x 256 thr (full chip). WG g owns bins
//       l=4g..4g+3 and mirrors 4095-l, so each spectral pair (k, 8192-k)
//       completes in-WG. Computes P[l] = sum_d T[d]*Y[(l+d)&8191] (Dirichlet
//       odd bins of H = rfft_16384(pad(irfft_8192(K_hat)))), per-WG S_K
//       reduce, and writes the sigma-permuted pair tables
//         even pair f1=2l   : Ta[m]=Y[l]/8192,        Tb[m]=Y[4096-l]/8192
//         odd  pair f1=2l+1 : Ta[m]=(S_K+iP[l])/8192^2, Tb: mirror
//       with m = sig8192(f1)>>1; WG0 writes self-pair m=4096.
//       (Same Ta/Tb contract as rounds 2-3 — conv untouched.)
//  C) s4_conv_kernel : per batch (1024 WGs, 512 thr, 64KB LDS):
//       pack -> DIF FFT-8192 -> pointwise pair loop -> DIT IFFT -> y.
//       (byte-identical to round 2/3 — verified)
//
// LDS addresses go through SW(x) = x ^ ((x>>4)&15) to kill bank conflicts.

#define TPB 512

__device__ __forceinline__ int SW(int x){ return x ^ ((x >> 4) & 15); }

__device__ __forceinline__ float2 cadd(float2 a, float2 b){ return make_float2(a.x+b.x, a.y+b.y); }
__device__ __forceinline__ float2 csub(float2 a, float2 b){ return make_float2(a.x-b.x, a.y-b.y); }
__device__ __forceinline__ float2 cmulf(float2 a, float2 b){
  return make_float2(a.x*b.x - a.y*b.y, a.x*b.y + a.y*b.x);
}
template<int SGN>
__device__ __forceinline__ float2 muli(float2 v){
  return (SGN > 0) ? make_float2(-v.y, v.x) : make_float2(v.y, -v.x);
}

template<int SGN>   // -1: forward DFT8; +1: conj (unscaled inverse)
__device__ __forceinline__ void dft8(const float2* a, float2* X){
  const float C  = 0.70710678118654752f;
  const float SC = (SGN > 0) ? C : -C;
  float2 e0=cadd(a[0],a[4]), e1=csub(a[0],a[4]);
  float2 e2=cadd(a[2],a[6]), e3=csub(a[2],a[6]);
  float2 f0=cadd(a[1],a[5]), f1=csub(a[1],a[5]);
  float2 f2=cadd(a[3],a[7]), f3=csub(a[3],a[7]);
  float2 ie3 = muli<SGN>(e3), if3 = muli<SGN>(f3);
  float2 E0=cadd(e0,e2), E2=csub(e0,e2);
  float2 E1=cadd(e1,ie3), E3=csub(e1,ie3);
  float2 O0=cadd(f0,f2), O2=csub(f0,f2);
  float2 O1=cadd(f1,if3), O3=csub(f1,if3);
  float2 O2r = muli<SGN>(O2);
  float2 O1r = cmulf(O1, make_float2(C,  SC));
  float2 O3r = cmulf(O3, make_float2(-C, SC));
  X[0]=cadd(E0,O0);  X[4]=csub(E0,O0);
  X[1]=cadd(E1,O1r); X[5]=csub(E1,O1r);
  X[2]=cadd(E2,O2r); X[6]=csub(E2,O2r);
  X[3]=cadd(E3,O3r); X[7]=csub(E3,O3r);
}

template<int NFFT, int T>
__device__ void dif8_stage(float2* S, int size, int tid){
  const int t = size >> 3;
  const float ang = -6.283185307179586f / (float)size;
  for (int u = tid; u < (NFFT >> 3); u += T){
    int j = u & (t - 1);
    int base = ((u - j) << 3) + j;
    float2 a[8], X[8];
#pragma unroll
    for (int q = 0; q < 8; q++) a[q] = S[SW(base + q*t)];
    dft8<-1>(a, X);
    if (t > 1){
      float sn, cn; __sincosf(ang * (float)j, &sn, &cn);
      float2 w = make_float2(cn, sn), wq = w;
#pragma unroll
      for (int q = 1; q < 8; q++){ X[q] = cmulf(X[q], wq); wq = cmulf(wq, w); }
    }
#pragma unroll
    for (int q = 0; q < 8; q++) S[SW(base + q*t)] = X[q];
  }
}

template<int NFFT, int T>
__device__ void dit8_stage(float2* S, int size, int tid){
  const int t = size >> 3;
  const float ang = 6.283185307179586f / (float)size;
  for (int u = tid; u < (NFFT >> 3); u += T){
    int j = u & (t - 1);
    int base = ((u - j) << 3) + j;
    float2 a[8], X[8];
#pragma unroll
    for (int q = 0; q < 8; q++) a[q] = S[SW(base + q*t)];
    if (t > 1){
      float sn, cn; __sincosf(ang * (float)j, &sn, &cn);
      float2 w = make_float2(cn, sn), wq = w;
#pragma unroll
      for (int q = 1; q < 8; q++){ a[q] = cmulf(a[q], wq); wq = cmulf(wq, w); }
    }
    dft8<1>(a, X);
#pragma unroll
    for (int q = 0; q < 8; q++) S[SW(base + q*t)] = X[q];
  }
}

template<int NFFT, int T>
__device__ void r2_stage(float2* S, int tid){
  float4* S4 = reinterpret_cast<float4*>(S);
  for (int f = tid; f < (NFFT >> 1); f += T){
    int V  = (f >> 3) & 15;
    int fp = f ^ (V >> 1);
    float4 v = S4[fp];
    float sg = (V & 1) ? -1.0f : 1.0f;
    float4 r;
    r.x = sg*v.x + v.z;  r.y = sg*v.y + v.w;
    r.z = v.x - sg*v.z;  r.w = v.y - sg*v.w;
    S4[fp] = r;
  }
}

__device__ __forceinline__ int sig8192(int k){
  return ((k & 7) << 10) | (((k >> 3) & 7) << 7) | (((k >> 6) & 7) << 4)
       | (((k >> 9) & 7) << 1) | ((k >> 12) & 1);
}
__device__ __forceinline__ int siginv_even(int m){  // k such that sig8192(k) == 2m
  return (m >> 9) | (((m >> 6) & 7) << 3) | (((m >> 3) & 7) << 6) | ((m & 7) << 9);
}

// A) K_hat (fp64) -> Hermitian-forced Y[0..8191]; cot table T[0..8191]  [r3-verified]
__global__ __launch_bounds__(256) void s4_khat_kernel(const float* __restrict__ Bp,
                                                      const float* __restrict__ Cp,
                                                      double2* __restrict__ Y,
                                                      double* __restrict__ T){
  const int l = blockIdx.x * blockDim.x + threadIdx.x;   // 0..8191
  const double PI = 3.14159265358979323846264338327950288;
  if (l < 8192){
    double phi = PI * (double)(2*l - 1) / 16384.0;
    double s, c; sincos(phi, &s, &c);
    T[l] = c / s;          // cot(pi*(2d-1)/16384)
  }
  if (l > 4096) return;
  double th = (2.0 * PI / 8192.0) * (double)l;
  double wr = cos(th), wi = sin(th);
  double ux = 1.0 + wr, uy = wi;
  double vx = 1.0 - wr, vy = -wi;
  double gx = 20.0 * vx, gy = 20.0 * vy;
  double s00x=0,s00y=0, s01x=0,s01y=0, s10x=0,s10y=0, s11x=0,s11y=0;
  for (int n = 0; n < 64; n++){
    double Bn = (double)Bp[n], Cn = (double)Cp[n];
    double Pn = sqrt((double)n + 0.5);
    double lx = -0.5, ly = PI * (double)n;
    double dx = gx - (ux*lx - uy*ly);
    double dy = gy - (ux*ly + uy*lx);
    double inv2 = 2.0 / (dx*dx + dy*dy);
    double cix = dx * inv2, ciy = -dy * inv2;
    double w00 = Cn*Bn, w01 = Cn*Pn, w10 = Pn*Bn, w11 = Pn*Pn;
    s00x += w00*cix; s00y += w00*ciy;
    s01x += w01*cix; s01y += w01*ciy;
    s10x += w10*cix; s10y += w10*ciy;
    s11x += w11*cix; s11y += w11*ciy;
  }
  double hux = 0.5*ux, huy = 0.5*uy;
  double k11x = hux*s11x - huy*s11y;
  double k11y = hux*s11y + huy*s11x;
  double p1x = 1.0 + k11x, p1y = k11y;
  double t1x = s01x*p1x - s01y*p1y, t1y = s01x*p1y + s01y*p1x;
  double t2x = t1x*s10x - t1y*s10y, t2y = t1x*s10y + t1y*s10x;
  double crx = t2x*hux - t2y*huy,   cry = t2x*huy + t2y*hux;
  double vr = s00x - crx, vi = s00y - cry;
  if (l == 0)         Y[0]    = make_double2(vr, 0.0);
  else if (l == 4096) Y[4096] = make_double2(vr, 0.0);
  else { Y[l] = make_double2(vr, vi); Y[8192 - l] = make_double2(vr, -vi); }
}

// B) Dirichlet odd bins + S_K + table writes, full chip (512 WGs x 256 thr)
__global__ __launch_bounds__(256) void s4_tabs_kernel(const double2* __restrict__ Y,
                                                      const double* __restrict__ T,
                                                      float2* __restrict__ Ta,
                                                      float2* __restrict__ Tb){
  __shared__ double2 red[256][9];    // [..][0..3]=P(lA+j) [..][4..7]=P(lB+j) [..][8]=S_K
  const int tid = threadIdx.x;
  const int g   = blockIdx.x;        // 0..511
  const int lA  = g * 4;             // owner bins lA..lA+3   (0..2047)
  const int lB  = 4092 - lA;         // mirror bins lB..lB+3  (2048..4095)
  const int d0  = tid * 32;          // this thread's d-chunk [d0, d0+32)
  double2 wA[4], wB[4];
#pragma unroll
  for (int j = 0; j < 4; j++){
    wA[j] = Y[(lA + d0 + j) & 8191];
    wB[j] = Y[(lB + d0 + j) & 8191];
  }
  double aAr[4]={0,0,0,0}, aAi[4]={0,0,0,0};
  double aBr[4]={0,0,0,0}, aBi[4]={0,0,0,0};
  double skr = 0.0, ski = 0.0;
#pragma unroll 4
  for (int s = 0; s < 32; s++){
    const int d = d0 + s;
    double t = T[d];
    double2 ys = Y[d];                       // coalesced; S_K partial
    skr += ys.x; ski += ys.y;
    double2 nA = Y[(lA + d + 4) & 8191];
    double2 nB = Y[(lB + d + 4) & 8191];
#pragma unroll
    for (int j = 0; j < 4; j++){
      aAr[j] += t * wA[j].x;  aAi[j] += t * wA[j].y;
      aBr[j] += t * wB[j].x;  aBi[j] += t * wB[j].y;
    }
#pragma unroll
    for (int j = 0; j < 3; j++){ wA[j] = wA[j+1]; wB[j] = wB[j+1]; }
    wA[3] = nA; wB[3] = nB;
  }
#pragma unroll
  for (int j = 0; j < 4; j++){
    red[tid][j]     = make_double2(aAr[j], aAi[j]);
    red[tid][4 + j] = make_double2(aBr[j], aBi[j]);
  }
  red[tid][8] = make_double2(skr, ski);
  __syncthreads();
  for (int h = 128; h > 0; h >>= 1){
    if (tid < h){
#pragma unroll
      for (int j = 0; j < 9; j++){
        red[tid][j].x += red[tid + h][j].x;
        red[tid][j].y += red[tid + h][j].y;
      }
    }
    __syncthreads();
  }
  if (tid < 4){
    const int l = lA + tid;                        // owner bin, l < 2048
    const double SKr = red[0][8].x, SKi = red[0][8].y;
    const double Por = red[0][tid].x, Poi = red[0][tid].y;              // P[l]
    const double Pmr = red[0][4 + (3 - tid)].x, Pmi = red[0][4 + (3 - tid)].y; // P[4095-l]
    // odd pair: f1 = 2l+1, f2 = 8192-f1 = 2(4095-l)+1
    const double q = (1.0/8192.0) * (1.0/8192.0);
    int mo = sig8192(2*l + 1) >> 1;
    Ta[mo] = make_float2((float)((SKr - Poi) * q), (float)((SKi + Por) * q));
    Tb[mo] = make_float2((float)((SKr - Pmi) * q), (float)((SKi + Pmr) * q));
    // even pair: f1 = 2l, H[2l] = Y[l]; f2 = 8192-2l, H[f2] = Y[4096-l]
    const double sc = 1.0/8192.0;
    int me = sig8192(2*l) >> 1;
    double2 ye = Y[l];
    double2 yo = Y[4096 - l];
    Ta[me] = make_float2((float)(ye.x * sc), (float)(ye.y * sc));
    Tb[me] = make_float2((float)(yo.x * sc), (float)(yo.y * sc));
  }
  if (g == 0 && tid == 4){                         // self-pair m=4096 (f=4096)
    double2 yn = Y[2048];
    float2 v = make_float2((float)(yn.x / 8192.0), (float)(yn.y / 8192.0));
    Ta[4096] = v; Tb[4096] = v;
  }
}

// C) conv — byte-identical to rounds 2/3 (verified)
__global__ __launch_bounds__(TPB, 4) void s4_conv_kernel(const float2* __restrict__ x2,
                                                         const float2* __restrict__ Ta,
                                                         const float2* __restrict__ Tb,
                                                         float2* __restrict__ y2){
  __shared__ __align__(16) float2 S[8192];
  const int tid = threadIdx.x;
  const int b = blockIdx.x;
  const float2* xb = x2 + (size_t)b * 4096;
  for (int n = tid; n < 4096; n += TPB) S[SW(n)] = xb[n];
  for (int n = 4096 + tid; n < 8192; n += TPB) S[n] = make_float2(0.f, 0.f);
  __syncthreads();
  dif8_stage<8192,TPB>(S, 8192, tid); __syncthreads();
  dif8_stage<8192,TPB>(S, 1024, tid); __syncthreads();
  dif8_stage<8192,TPB>(S, 128, tid);  __syncthreads();
  dif8_stage<8192,TPB>(S, 16, tid);   __syncthreads();
  r2_stage<8192,TPB>(S, tid);         __syncthreads();
  for (int m = tid; m < 4097; m += TPB){
    int s, k;
    if (m == 4096){ s = 1; k = 4096; }
    else          { s = 2*m; k = siginv_even(m); }
    int j = (8192 - k) & 8191;
    int sj = sig8192(j);
    int as = SW(s), aj = SW(sj);
    float2 Zk = S[as], Zj = S[aj];
    float2 A  = make_float2(0.5f*(Zk.x + Zj.x), 0.5f*(Zk.y - Zj.y));
    float2 Bc = make_float2(0.5f*(Zk.x - Zj.x), 0.5f*(Zk.y + Zj.y));
    float sn, cn; __sincosf(-3.834951969714103e-4f * (float)k, &sn, &cn);
    float2 tb  = cmulf(make_float2(cn, sn), Bc);
    float2 tcb = cmulf(make_float2(cn, -sn), make_float2(Bc.x, -Bc.y));
    float2 Xk = make_float2(A.x + tb.y,  A.y - tb.x);
    float2 Xm = make_float2(A.x + tcb.y, -A.y - tcb.x);
    float2 Yk = cmulf(Xk, Ta[m]);
    float2 Ym = cmulf(Xm, Tb[m]);
    float2 E = make_float2(0.5f*(Yk.x + Ym.x), 0.5f*(Yk.y - Ym.y));
    float2 D = make_float2(0.5f*(Yk.x - Ym.x), 0.5f*(Yk.y + Ym.y));
    float2 Od = cmulf(make_float2(cn, -sn), D);
    S[as] = make_float2(E.x - Od.y, E.y + Od.x);
    if (aj != as)
      S[aj] = make_float2(E.x + Od.y, Od.x - E.y);
  }
  __syncthreads();
  r2_stage<8192,TPB>(S, tid);         __syncthreads();
  dit8_stage<8192,TPB>(S, 16, tid);   __syncthreads();
  dit8_stage<8192,TPB>(S, 128, tid);  __syncthreads();
  dit8_stage<8192,TPB>(S, 1024, tid); __syncthreads();
  dit8_stage<8192,TPB>(S, 8192, tid); __syncthreads();
  float2* yb = y2 + (size_t)b * 4096;
  for (int n = tid; n < 4096; n += TPB) yb[n] = S[SW(n)];
}

extern "C" void kernel_launch(void* const* d_in, const int* in_sizes, int n_in,
                              void* d_out, int out_size, void* d_ws, size_t ws_size,
                              hipStream_t stream){
  (void)n_in; (void)out_size; (void)ws_size;
  const float* x  = (const float*)d_in[0];
  const float* Bp = (const float*)d_in[1];
  const float* Cp = (const float*)d_in[2];
  // ws: Y[8192] double2 @0 (128K), T[8192] double @131072 (64K),
  //     Ta[4097] float2 @196608 (32776->33024), Tb[4097] float2 @229632  (~257 KB)
  double2* Yt = (double2*)d_ws;
  double*  Tt = (double*)((char*)d_ws + 131072);
  float2*  Ta = (float2*)((char*)d_ws + 196608);
  float2*  Tb = (float2*)((char*)d_ws + 229632);
  const int batch = in_sizes[0] / 8192;
  hipLaunchKernelGGL(s4_khat_kernel, dim3(32), dim3(256), 0, stream, Bp, Cp, Yt, Tt);
  hipLaunchKernelGGL(s4_tabs_kernel, dim3(512), dim3(256), 0, stream, Yt, Tt, Ta, Tb);
  hipLaunchKernelGGL(s4_conv_kernel, dim3(batch), dim3(TPB), 0, stream,
                     (const float2*)x, (const float2*)Ta, (const float2*)Tb, (float2*)d_out);
}

// Round 5
// 164.485 us; speedup vs baseline: 1.1267x; 1.1267x over previous
//
#include <hip/hip_runtime.h>
#include <math.h>

// S4 DPLR kernel + batched causal convolution via custom packed-real FFTs.
//
//  A) s4_khat_kernel : Y[l] = Hermitian-forced K_hat (fp64, stable Cauchy form,
//       c*inv = 2/(20(1-w) - (1+w)Lambda)); also cot table T[d].  [verified r3/r4]
//  B) s4_tabs_kernel : 512 WGs x 256 thr. WG g owns bins l=4g..4g+3 and
//       mirrors 4095-l. v2: Y staged to LDS (fp32) with coalesced loads;
//       Dirichlet sum P[l] = sum_d T[d]*Y[(l+d)&8191] runs d = tid+256s so
//       T loads are coalesced and window reads are conflict-free LDS.
//       (r4's version did the same sums with 64-line/wave global gathers —
//        ~110 us of TA serialization. Math identical; fp64 accumulation.)
//       Table contract unchanged:
//         even pair f1=2l   : Ta[m]=Y[l]/8192,          Tb[m]=Y[4096-l]/8192
//         odd  pair f1=2l+1 : Ta[m]=(S_K+iP[l])/8192^2,  Tb: mirror
//       with m = sig8192(f1)>>1; WG0 writes self-pair m=4096.
//  C) s4_conv_kernel : per batch (1024 WGs, 512 thr, 64KB LDS):
//       pack -> DIF FFT-8192 -> pointwise pair loop -> DIT IFFT -> y.
//       (byte-identical to rounds 2-4 — verified)
//
// LDS addresses in conv go through SW(x) = x ^ ((x>>4)&15) to kill bank conflicts.

#define TPB 512

__device__ __forceinline__ int SW(int x){ return x ^ ((x >> 4) & 15); }

__device__ __forceinline__ float2 cadd(float2 a, float2 b){ return make_float2(a.x+b.x, a.y+b.y); }
__device__ __forceinline__ float2 csub(float2 a, float2 b){ return make_float2(a.x-b.x, a.y-b.y); }
__device__ __forceinline__ float2 cmulf(float2 a, float2 b){
  return make_float2(a.x*b.x - a.y*b.y, a.x*b.y + a.y*b.x);
}
template<int SGN>
__device__ __forceinline__ float2 muli(float2 v){
  return (SGN > 0) ? make_float2(-v.y, v.x) : make_float2(v.y, -v.x);
}

template<int SGN>   // -1: forward DFT8; +1: conj (unscaled inverse)
__device__ __forceinline__ void dft8(const float2* a, float2* X){
  const float C  = 0.70710678118654752f;
  const float SC = (SGN > 0) ? C : -C;
  float2 e0=cadd(a[0],a[4]), e1=csub(a[0],a[4]);
  float2 e2=cadd(a[2],a[6]), e3=csub(a[2],a[6]);
  float2 f0=cadd(a[1],a[5]), f1=csub(a[1],a[5]);
  float2 f2=cadd(a[3],a[7]), f3=csub(a[3],a[7]);
  float2 ie3 = muli<SGN>(e3), if3 = muli<SGN>(f3);
  float2 E0=cadd(e0,e2), E2=csub(e0,e2);
  float2 E1=cadd(e1,ie3), E3=csub(e1,ie3);
  float2 O0=cadd(f0,f2), O2=csub(f0,f2);
  float2 O1=cadd(f1,if3), O3=csub(f1,if3);
  float2 O2r = muli<SGN>(O2);
  float2 O1r = cmulf(O1, make_float2(C,  SC));
  float2 O3r = cmulf(O3, make_float2(-C, SC));
  X[0]=cadd(E0,O0);  X[4]=csub(E0,O0);
  X[1]=cadd(E1,O1r); X[5]=csub(E1,O1r);
  X[2]=cadd(E2,O2r); X[6]=csub(E2,O2r);
  X[3]=cadd(E3,O3r); X[7]=csub(E3,O3r);
}

template<int NFFT, int T>
__device__ void dif8_stage(float2* S, int size, int tid){
  const int t = size >> 3;
  const float ang = -6.283185307179586f / (float)size;
  for (int u = tid; u < (NFFT >> 3); u += T){
    int j = u & (t - 1);
    int base = ((u - j) << 3) + j;
    float2 a[8], X[8];
#pragma unroll
    for (int q = 0; q < 8; q++) a[q] = S[SW(base + q*t)];
    dft8<-1>(a, X);
    if (t > 1){
      float sn, cn; __sincosf(ang * (float)j, &sn, &cn);
      float2 w = make_float2(cn, sn), wq = w;
#pragma unroll
      for (int q = 1; q < 8; q++){ X[q] = cmulf(X[q], wq); wq = cmulf(wq, w); }
    }
#pragma unroll
    for (int q = 0; q < 8; q++) S[SW(base + q*t)] = X[q];
  }
}

template<int NFFT, int T>
__device__ void dit8_stage(float2* S, int size, int tid){
  const int t = size >> 3;
  const float ang = 6.283185307179586f / (float)size;
  for (int u = tid; u < (NFFT >> 3); u += T){
    int j = u & (t - 1);
    int base = ((u - j) << 3) + j;
    float2 a[8], X[8];
#pragma unroll
    for (int q = 0; q < 8; q++) a[q] = S[SW(base + q*t)];
    if (t > 1){
      float sn, cn; __sincosf(ang * (float)j, &sn, &cn);
      float2 w = make_float2(cn, sn), wq = w;
#pragma unroll
      for (int q = 1; q < 8; q++){ a[q] = cmulf(a[q], wq); wq = cmulf(wq, w); }
    }
    dft8<1>(a, X);
#pragma unroll
    for (int q = 0; q < 8; q++) S[SW(base + q*t)] = X[q];
  }
}

template<int NFFT, int T>
__device__ void r2_stage(float2* S, int tid){
  float4* S4 = reinterpret_cast<float4*>(S);
  for (int f = tid; f < (NFFT >> 1); f += T){
    int V  = (f >> 3) & 15;
    int fp = f ^ (V >> 1);
    float4 v = S4[fp];
    float sg = (V & 1) ? -1.0f : 1.0f;
    float4 r;
    r.x = sg*v.x + v.z;  r.y = sg*v.y + v.w;
    r.z = v.x - sg*v.z;  r.w = v.y - sg*v.w;
    S4[fp] = r;
  }
}

__device__ __forceinline__ int sig8192(int k){
  return ((k & 7) << 10) | (((k >> 3) & 7) << 7) | (((k >> 6) & 7) << 4)
       | (((k >> 9) & 7) << 1) | ((k >> 12) & 1);
}
__device__ __forceinline__ int siginv_even(int m){  // k such that sig8192(k) == 2m
  return (m >> 9) | (((m >> 6) & 7) << 3) | (((m >> 3) & 7) << 6) | ((m & 7) << 9);
}

// A) K_hat (fp64) -> Hermitian-forced Y[0..8191]; cot table T[0..8191]  [verified]
__global__ __launch_bounds__(256) void s4_khat_kernel(const float* __restrict__ Bp,
                                                      const float* __restrict__ Cp,
                                                      double2* __restrict__ Y,
                                                      double* __restrict__ T){
  const int l = blockIdx.x * blockDim.x + threadIdx.x;   // 0..8191
  const double PI = 3.14159265358979323846264338327950288;
  if (l < 8192){
    double phi = PI * (double)(2*l - 1) / 16384.0;
    double s, c; sincos(phi, &s, &c);
    T[l] = c / s;          // cot(pi*(2d-1)/16384)
  }
  if (l > 4096) return;
  double th = (2.0 * PI / 8192.0) * (double)l;
  double wr = cos(th), wi = sin(th);
  double ux = 1.0 + wr, uy = wi;
  double vx = 1.0 - wr, vy = -wi;
  double gx = 20.0 * vx, gy = 20.0 * vy;
  double s00x=0,s00y=0, s01x=0,s01y=0, s10x=0,s10y=0, s11x=0,s11y=0;
  for (int n = 0; n < 64; n++){
    double Bn = (double)Bp[n], Cn = (double)Cp[n];
    double Pn = sqrt((double)n + 0.5);
    double lx = -0.5, ly = PI * (double)n;
    double dx = gx - (ux*lx - uy*ly);
    double dy = gy - (ux*ly + uy*lx);
    double inv2 = 2.0 / (dx*dx + dy*dy);
    double cix = dx * inv2, ciy = -dy * inv2;
    double w00 = Cn*Bn, w01 = Cn*Pn, w10 = Pn*Bn, w11 = Pn*Pn;
    s00x += w00*cix; s00y += w00*ciy;
    s01x += w01*cix; s01y += w01*ciy;
    s10x += w10*cix; s10y += w10*ciy;
    s11x += w11*cix; s11y += w11*ciy;
  }
  double hux = 0.5*ux, huy = 0.5*uy;
  double k11x = hux*s11x - huy*s11y;
  double k11y = hux*s11y + huy*s11x;
  double p1x = 1.0 + k11x, p1y = k11y;
  double t1x = s01x*p1x - s01y*p1y, t1y = s01x*p1y + s01y*p1x;
  double t2x = t1x*s10x - t1y*s10y, t2y = t1x*s10y + t1y*s10x;
  double crx = t2x*hux - t2y*huy,   cry = t2x*huy + t2y*hux;
  double vr = s00x - crx, vi = s00y - cry;
  if (l == 0)         Y[0]    = make_double2(vr, 0.0);
  else if (l == 4096) Y[4096] = make_double2(vr, 0.0);
  else { Y[l] = make_double2(vr, vi); Y[8192 - l] = make_double2(vr, -vi); }
}

// B) v2: LDS-staged Dirichlet odd bins + S_K + table writes (512 WGs x 256 thr)
__global__ __launch_bounds__(256) void s4_tabs_kernel(const double2* __restrict__ Y,
                                                      const double* __restrict__ T,
                                                      float2* __restrict__ Ta,
                                                      float2* __restrict__ Tb){
  __shared__ __align__(16) float2 Ys[8192];   // 64 KB; reused as red[][] after barrier
  const int tid = threadIdx.x;
  const int g   = blockIdx.x;        // 0..511
  const int lA  = g * 4;             // owner bins lA..lA+3   (0..2047)
  const int lB  = 4092 - lA;         // mirror bins lB..lB+3  (2048..4095)
  // stage Y (coalesced fp64 loads -> fp32 LDS) and accumulate S_K partials
  double skr = 0.0, ski = 0.0;
  for (int m = tid; m < 8192; m += 256){
    double2 v = Y[m];
    skr += v.x; ski += v.y;
    Ys[m] = make_float2((float)v.x, (float)v.y);
  }
  __syncthreads();
  // Dirichlet: d = tid + 256*s; T coalesced from global, windows from LDS
  double aAr[4]={0,0,0,0}, aAi[4]={0,0,0,0};
  double aBr[4]={0,0,0,0}, aBi[4]={0,0,0,0};
#pragma unroll 4
  for (int s = 0; s < 32; s++){
    const int d = (s << 8) + tid;
    const double t = T[d];
#pragma unroll
    for (int j = 0; j < 4; j++){
      float2 va = Ys[(lA + j + d) & 8191];
      float2 vb = Ys[(lB + j + d) & 8191];
      aAr[j] += t * (double)va.x;  aAi[j] += t * (double)va.y;
      aBr[j] += t * (double)vb.x;  aBi[j] += t * (double)vb.y;
    }
  }
  __syncthreads();                   // all Ys reads done; alias reduction scratch
  double2 (*red)[9] = (double2 (*)[9])(void*)Ys;   // 256*9*16 = 36864 B < 64 KB
#pragma unroll
  for (int j = 0; j < 4; j++){
    red[tid][j]     = make_double2(aAr[j], aAi[j]);
    red[tid][4 + j] = make_double2(aBr[j], aBi[j]);
  }
  red[tid][8] = make_double2(skr, ski);
  __syncthreads();
  for (int h = 128; h > 0; h >>= 1){
    if (tid < h){
#pragma unroll
      for (int j = 0; j < 9; j++){
        red[tid][j].x += red[tid + h][j].x;
        red[tid][j].y += red[tid + h][j].y;
      }
    }
    __syncthreads();
  }
  if (tid < 4){                                    // write logic verbatim from r4
    const int l = lA + tid;                        // owner bin, l < 2048
    const double SKr = red[0][8].x, SKi = red[0][8].y;
    const double Por = red[0][tid].x, Poi = red[0][tid].y;                     // P[l]
    const double Pmr = red[0][4 + (3 - tid)].x, Pmi = red[0][4 + (3 - tid)].y; // P[4095-l]
    // odd pair: f1 = 2l+1, f2 = 8192-f1 = 2(4095-l)+1
    const double q = (1.0/8192.0) * (1.0/8192.0);
    int mo = sig8192(2*l + 1) >> 1;
    Ta[mo] = make_float2((float)((SKr - Poi) * q), (float)((SKi + Por) * q));
    Tb[mo] = make_float2((float)((SKr - Pmi) * q), (float)((SKi + Pmr) * q));
    // even pair: f1 = 2l, H[2l] = Y[l]; f2 = 8192-2l, H[f2] = Y[4096-l]
    const double sc = 1.0/8192.0;
    int me = sig8192(2*l) >> 1;
    double2 ye = Y[l];
    double2 yo = Y[4096 - l];
    Ta[me] = make_float2((float)(ye.x * sc), (float)(ye.y * sc));
    Tb[me] = make_float2((float)(yo.x * sc), (float)(yo.y * sc));
  }
  if (g == 0 && tid == 4){                         // self-pair m=4096 (f=4096)
    double2 yn = Y[2048];
    float2 v = make_float2((float)(yn.x / 8192.0), (float)(yn.y / 8192.0));
    Ta[4096] = v; Tb[4096] = v;
  }
}

// C) conv — byte-identical to rounds 2-4 (verified)
__global__ __launch_bounds__(TPB, 4) void s4_conv_kernel(const float2* __restrict__ x2,
                                                         const float2* __restrict__ Ta,
                                                         const float2* __restrict__ Tb,
                                                         float2* __restrict__ y2){
  __shared__ __align__(16) float2 S[8192];
  const int tid = threadIdx.x;
  const int b = blockIdx.x;
  const float2* xb = x2 + (size_t)b * 4096;
  for (int n = tid; n < 4096; n += TPB) S[SW(n)] = xb[n];
  for (int n = 4096 + tid; n < 8192; n += TPB) S[n] = make_float2(0.f, 0.f);
  __syncthreads();
  dif8_stage<8192,TPB>(S, 8192, tid); __syncthreads();
  dif8_stage<8192,TPB>(S, 1024, tid); __syncthreads();
  dif8_stage<8192,TPB>(S, 128, tid);  __syncthreads();
  dif8_stage<8192,TPB>(S, 16, tid);   __syncthreads();
  r2_stage<8192,TPB>(S, tid);         __syncthreads();
  for (int m = tid; m < 4097; m += TPB){
    int s, k;
    if (m == 4096){ s = 1; k = 4096; }
    else          { s = 2*m; k = siginv_even(m); }
    int j = (8192 - k) & 8191;
    int sj = sig8192(j);
    int as = SW(s), aj = SW(sj);
    float2 Zk = S[as], Zj = S[aj];
    float2 A  = make_float2(0.5f*(Zk.x + Zj.x), 0.5f*(Zk.y - Zj.y));
    float2 Bc = make_float2(0.5f*(Zk.x - Zj.x), 0.5f*(Zk.y + Zj.y));
    float sn, cn; __sincosf(-3.834951969714103e-4f * (float)k, &sn, &cn);
    float2 tb  = cmulf(make_float2(cn, sn), Bc);
    float2 tcb = cmulf(make_float2(cn, -sn), make_float2(Bc.x, -Bc.y));
    float2 Xk = make_float2(A.x + tb.y,  A.y - tb.x);
    float2 Xm = make_float2(A.x + tcb.y, -A.y - tcb.x);
    float2 Yk = cmulf(Xk, Ta[m]);
    float2 Ym = cmulf(Xm, Tb[m]);
    float2 E = make_float2(0.5f*(Yk.x + Ym.x), 0.5f*(Yk.y - Ym.y));
    float2 D = make_float2(0.5f*(Yk.x - Ym.x), 0.5f*(Yk.y + Ym.y));
    float2 Od = cmulf(make_float2(cn, -sn), D);
    S[as] = make_float2(E.x - Od.y, E.y + Od.x);
    if (aj != as)
      S[aj] = make_float2(E.x + Od.y, Od.x - E.y);
  }
  __syncthreads();
  r2_stage<8192,TPB>(S, tid);         __syncthreads();
  dit8_stage<8192,TPB>(S, 16, tid);   __syncthreads();
  dit8_stage<8192,TPB>(S, 128, tid);  __syncthreads();
  dit8_stage<8192,TPB>(S, 1024, tid); __syncthreads();
  dit8_stage<8192,TPB>(S, 8192, tid); __syncthreads();
  float2* yb = y2 + (size_t)b * 4096;
  for (int n = tid; n < 4096; n += TPB) yb[n] = S[SW(n)];
}

extern "C" void kernel_launch(void* const* d_in, const int* in_sizes, int n_in,
                              void* d_out, int out_size, void* d_ws, size_t ws_size,
                              hipStream_t stream){
  (void)n_in; (void)out_size; (void)ws_size;
  const float* x  = (const float*)d_in[0];
  const float* Bp = (const float*)d_in[1];
  const float* Cp = (const float*)d_in[2];
  // ws: Y[8192] double2 @0 (128K), T[8192] double @131072 (64K),
  //     Ta[4097] float2 @196608, Tb[4097] float2 @229632  (~257 KB)
  double2* Yt = (double2*)d_ws;
  double*  Tt = (double*)((char*)d_ws + 131072);
  float2*  Ta = (float2*)((char*)d_ws + 196608);
  float2*  Tb = (float2*)((char*)d_ws + 229632);
  const int batch = in_sizes[0] / 8192;
  hipLaunchKernelGGL(s4_khat_kernel, dim3(32), dim3(256), 0, stream, Bp, Cp, Yt, Tt);
  hipLaunchKernelGGL(s4_tabs_kernel, dim3(512), dim3(256), 0, stream, Yt, Tt, Ta, Tb);
  hipLaunchKernelGGL(s4_conv_kernel, dim3(batch), dim3(TPB), 0, stream,
                     (const float2*)x, (const float2*)Ta, (const float2*)Tb, (float2*)d_out);
}

// Round 6
// 158.223 us; speedup vs baseline: 1.1713x; 1.0396x over previous
//
#include <hip/hip_runtime.h>
#include <math.h>

// S4 DPLR kernel + batched causal convolution via custom packed-real FFTs.
//
//  A) s4_khat_kernel v2 : wave-per-l Cauchy sum. Lane n owns pole n (one fp64
//       div + sqrt per lane instead of a 64-deep serial chain), __shfl_xor
//       butterfly reduces the 8 accumulators; 1025 WGs -> full chip.
//       WGs 1025..1056 write the cot table T[d] (WG-granular branch).
//       Same fp64 math as r3-r5 (verified absmax 1.0); r5's version ran
//       17-32 blocks x 64-iter serial fp64 chains ≈ 50-60 us unhidden.
//  B) s4_tabs_kernel : byte-identical to round 5 (verified).
//       LDS-staged Dirichlet odd bins + S_K + sigma-permuted pair tables:
//         even pair f1=2l   : Ta[m]=Y[l]/8192,          Tb[m]=Y[4096-l]/8192
//         odd  pair f1=2l+1 : Ta[m]=(S_K+iP[l])/8192^2,  Tb: mirror
//  C) s4_conv_kernel : byte-identical to rounds 2-5 (verified).
//       pack -> DIF FFT-8192 -> pointwise pair loop -> DIT IFFT -> y.
//
// LDS addresses in conv go through SW(x) = x ^ ((x>>4)&15) to kill bank conflicts.

#define TPB 512

__device__ __forceinline__ int SW(int x){ return x ^ ((x >> 4) & 15); }

__device__ __forceinline__ float2 cadd(float2 a, float2 b){ return make_float2(a.x+b.x, a.y+b.y); }
__device__ __forceinline__ float2 csub(float2 a, float2 b){ return make_float2(a.x-b.x, a.y-b.y); }
__device__ __forceinline__ float2 cmulf(float2 a, float2 b){
  return make_float2(a.x*b.x - a.y*b.y, a.x*b.y + a.y*b.x);
}
template<int SGN>
__device__ __forceinline__ float2 muli(float2 v){
  return (SGN > 0) ? make_float2(-v.y, v.x) : make_float2(v.y, -v.x);
}

template<int SGN>   // -1: forward DFT8; +1: conj (unscaled inverse)
__device__ __forceinline__ void dft8(const float2* a, float2* X){
  const float C  = 0.70710678118654752f;
  const float SC = (SGN > 0) ? C : -C;
  float2 e0=cadd(a[0],a[4]), e1=csub(a[0],a[4]);
  float2 e2=cadd(a[2],a[6]), e3=csub(a[2],a[6]);
  float2 f0=cadd(a[1],a[5]), f1=csub(a[1],a[5]);
  float2 f2=cadd(a[3],a[7]), f3=csub(a[3],a[7]);
  float2 ie3 = muli<SGN>(e3), if3 = muli<SGN>(f3);
  float2 E0=cadd(e0,e2), E2=csub(e0,e2);
  float2 E1=cadd(e1,ie3), E3=csub(e1,ie3);
  float2 O0=cadd(f0,f2), O2=csub(f0,f2);
  float2 O1=cadd(f1,if3), O3=csub(f1,if3);
  float2 O2r = muli<SGN>(O2);
  float2 O1r = cmulf(O1, make_float2(C,  SC));
  float2 O3r = cmulf(O3, make_float2(-C, SC));
  X[0]=cadd(E0,O0);  X[4]=csub(E0,O0);
  X[1]=cadd(E1,O1r); X[5]=csub(E1,O1r);
  X[2]=cadd(E2,O2r); X[6]=csub(E2,O2r);
  X[3]=cadd(E3,O3r); X[7]=csub(E3,O3r);
}

template<int NFFT, int T>
__device__ void dif8_stage(float2* S, int size, int tid){
  const int t = size >> 3;
  const float ang = -6.283185307179586f / (float)size;
  for (int u = tid; u < (NFFT >> 3); u += T){
    int j = u & (t - 1);
    int base = ((u - j) << 3) + j;
    float2 a[8], X[8];
#pragma unroll
    for (int q = 0; q < 8; q++) a[q] = S[SW(base + q*t)];
    dft8<-1>(a, X);
    if (t > 1){
      float sn, cn; __sincosf(ang * (float)j, &sn, &cn);
      float2 w = make_float2(cn, sn), wq = w;
#pragma unroll
      for (int q = 1; q < 8; q++){ X[q] = cmulf(X[q], wq); wq = cmulf(wq, w); }
    }
#pragma unroll
    for (int q = 0; q < 8; q++) S[SW(base + q*t)] = X[q];
  }
}

template<int NFFT, int T>
__device__ void dit8_stage(float2* S, int size, int tid){
  const int t = size >> 3;
  const float ang = 6.283185307179586f / (float)size;
  for (int u = tid; u < (NFFT >> 3); u += T){
    int j = u & (t - 1);
    int base = ((u - j) << 3) + j;
    float2 a[8], X[8];
#pragma unroll
    for (int q = 0; q < 8; q++) a[q] = S[SW(base + q*t)];
    if (t > 1){
      float sn, cn; __sincosf(ang * (float)j, &sn, &cn);
      float2 w = make_float2(cn, sn), wq = w;
#pragma unroll
      for (int q = 1; q < 8; q++){ a[q] = cmulf(a[q], wq); wq = cmulf(wq, w); }
    }
    dft8<1>(a, X);
#pragma unroll
    for (int q = 0; q < 8; q++) S[SW(base + q*t)] = X[q];
  }
}

template<int NFFT, int T>
__device__ void r2_stage(float2* S, int tid){
  float4* S4 = reinterpret_cast<float4*>(S);
  for (int f = tid; f < (NFFT >> 1); f += T){
    int V  = (f >> 3) & 15;
    int fp = f ^ (V >> 1);
    float4 v = S4[fp];
    float sg = (V & 1) ? -1.0f : 1.0f;
    float4 r;
    r.x = sg*v.x + v.z;  r.y = sg*v.y + v.w;
    r.z = v.x - sg*v.z;  r.w = v.y - sg*v.w;
    S4[fp] = r;
  }
}

__device__ __forceinline__ int sig8192(int k){
  return ((k & 7) << 10) | (((k >> 3) & 7) << 7) | (((k >> 6) & 7) << 4)
       | (((k >> 9) & 7) << 1) | ((k >> 12) & 1);
}
__device__ __forceinline__ int siginv_even(int m){  // k such that sig8192(k) == 2m
  return (m >> 9) | (((m >> 6) & 7) << 3) | (((m >> 3) & 7) << 6) | ((m & 7) << 9);
}

__device__ __forceinline__ double wsum64(double v){
#pragma unroll
  for (int m = 32; m > 0; m >>= 1) v += __shfl_xor(v, m, 64);
  return v;
}

// A) v2: wave-per-l Cauchy (fp64) -> Hermitian-forced Y[0..8191]; T via WGs>=1025
#define KHAT_CAUCHY_WGS 1025
__global__ __launch_bounds__(256) void s4_khat_kernel(const float* __restrict__ Bp,
                                                      const float* __restrict__ Cp,
                                                      double2* __restrict__ Y,
                                                      double* __restrict__ T){
  const double PI = 3.14159265358979323846264338327950288;
  const int bid = blockIdx.x;
  const int tid = threadIdx.x;
  if (bid >= KHAT_CAUCHY_WGS){
    // cot table T[d] = cot(pi*(2d-1)/16384), d in [0,8192)
    int d = (bid - KHAT_CAUCHY_WGS) * 256 + tid;
    double phi = PI * (double)(2*d - 1) / 16384.0;
    double s, c; sincos(phi, &s, &c);
    T[d] = c / s;
    return;
  }
  const int l = bid * 4 + (tid >> 6);     // one wave per bin l
  const int n = tid & 63;                 // lane owns pole n
  if (l > 4096) return;
  double th = (2.0 * PI / 8192.0) * (double)l;
  double wr = cos(th), wi = sin(th);
  double ux = 1.0 + wr, uy = wi;
  double vx = 1.0 - wr, vy = -wi;
  double gx = 20.0 * vx, gy = 20.0 * vy;
  // per-lane Cauchy term (identical formulas to r3-r5 inner loop body)
  double Bn = (double)Bp[n], Cn = (double)Cp[n];
  double Pn = sqrt((double)n + 0.5);
  double lx = -0.5, ly = PI * (double)n;
  double dx = gx - (ux*lx - uy*ly);
  double dy = gy - (ux*ly + uy*lx);
  double inv2 = 2.0 / (dx*dx + dy*dy);
  double cix = dx * inv2, ciy = -dy * inv2;
  double w00 = Cn*Bn, w01 = Cn*Pn, w10 = Pn*Bn, w11 = Pn*Pn;
  // butterfly-reduce the 8 sums across the wave (all lanes get totals)
  double s00x = wsum64(w00*cix), s00y = wsum64(w00*ciy);
  double s01x = wsum64(w01*cix), s01y = wsum64(w01*ciy);
  double s10x = wsum64(w10*cix), s10y = wsum64(w10*ciy);
  double s11x = wsum64(w11*cix), s11y = wsum64(w11*ciy);
  // tail combine (lane-uniform, identical to r3-r5)
  double hux = 0.5*ux, huy = 0.5*uy;
  double k11x = hux*s11x - huy*s11y;
  double k11y = hux*s11y + huy*s11x;
  double p1x = 1.0 + k11x, p1y = k11y;
  double t1x = s01x*p1x - s01y*p1y, t1y = s01x*p1y + s01y*p1x;
  double t2x = t1x*s10x - t1y*s10y, t2y = t1x*s10y + t1y*s10x;
  double crx = t2x*hux - t2y*huy,   cry = t2x*huy + t2y*hux;
  double vr = s00x - crx, vi = s00y - cry;
  // irfft semantics: imag dropped at DC/Nyquist; conj-extend upper half
  if (n == 0){
    if (l == 0 || l == 4096) Y[l] = make_double2(vr, 0.0);
    else                     Y[l] = make_double2(vr, vi);
  } else if (n == 1 && l != 0 && l != 4096){
    Y[8192 - l] = make_double2(vr, -vi);
  }
}

// B) LDS-staged Dirichlet odd bins + S_K + table writes — byte-identical to r5
__global__ __launch_bounds__(256) void s4_tabs_kernel(const double2* __restrict__ Y,
                                                      const double* __restrict__ T,
                                                      float2* __restrict__ Ta,
                                                      float2* __restrict__ Tb){
  __shared__ __align__(16) float2 Ys[8192];   // 64 KB; reused as red[][] after barrier
  const int tid = threadIdx.x;
  const int g   = blockIdx.x;        // 0..511
  const int lA  = g * 4;             // owner bins lA..lA+3   (0..2047)
  const int lB  = 4092 - lA;         // mirror bins lB..lB+3  (2048..4095)
  double skr = 0.0, ski = 0.0;
  for (int m = tid; m < 8192; m += 256){
    double2 v = Y[m];
    skr += v.x; ski += v.y;
    Ys[m] = make_float2((float)v.x, (float)v.y);
  }
  __syncthreads();
  double aAr[4]={0,0,0,0}, aAi[4]={0,0,0,0};
  double aBr[4]={0,0,0,0}, aBi[4]={0,0,0,0};
#pragma unroll 4
  for (int s = 0; s < 32; s++){
    const int d = (s << 8) + tid;
    const double t = T[d];
#pragma unroll
    for (int j = 0; j < 4; j++){
      float2 va = Ys[(lA + j + d) & 8191];
      float2 vb = Ys[(lB + j + d) & 8191];
      aAr[j] += t * (double)va.x;  aAi[j] += t * (double)va.y;
      aBr[j] += t * (double)vb.x;  aBi[j] += t * (double)vb.y;
    }
  }
  __syncthreads();
  double2 (*red)[9] = (double2 (*)[9])(void*)Ys;   // 256*9*16 = 36864 B < 64 KB
#pragma unroll
  for (int j = 0; j < 4; j++){
    red[tid][j]     = make_double2(aAr[j], aAi[j]);
    red[tid][4 + j] = make_double2(aBr[j], aBi[j]);
  }
  red[tid][8] = make_double2(skr, ski);
  __syncthreads();
  for (int h = 128; h > 0; h >>= 1){
    if (tid < h){
#pragma unroll
      for (int j = 0; j < 9; j++){
        red[tid][j].x += red[tid + h][j].x;
        red[tid][j].y += red[tid + h][j].y;
      }
    }
    __syncthreads();
  }
  if (tid < 4){
    const int l = lA + tid;
    const double SKr = red[0][8].x, SKi = red[0][8].y;
    const double Por = red[0][tid].x, Poi = red[0][tid].y;
    const double Pmr = red[0][4 + (3 - tid)].x, Pmi = red[0][4 + (3 - tid)].y;
    const double q = (1.0/8192.0) * (1.0/8192.0);
    int mo = sig8192(2*l + 1) >> 1;
    Ta[mo] = make_float2((float)((SKr - Poi) * q), (float)((SKi + Por) * q));
    Tb[mo] = make_float2((float)((SKr - Pmi) * q), (float)((SKi + Pmr) * q));
    const double sc = 1.0/8192.0;
    int me = sig8192(2*l) >> 1;
    double2 ye = Y[l];
    double2 yo = Y[4096 - l];
    Ta[me] = make_float2((float)(ye.x * sc), (float)(ye.y * sc));
    Tb[me] = make_float2((float)(yo.x * sc), (float)(yo.y * sc));
  }
  if (g == 0 && tid == 4){
    double2 yn = Y[2048];
    float2 v = make_float2((float)(yn.x / 8192.0), (float)(yn.y / 8192.0));
    Ta[4096] = v; Tb[4096] = v;
  }
}

// C) conv — byte-identical to rounds 2-5 (verified)
__global__ __launch_bounds__(TPB, 4) void s4_conv_kernel(const float2* __restrict__ x2,
                                                         const float2* __restrict__ Ta,
                                                         const float2* __restrict__ Tb,
                                                         float2* __restrict__ y2){
  __shared__ __align__(16) float2 S[8192];
  const int tid = threadIdx.x;
  const int b = blockIdx.x;
  const float2* xb = x2 + (size_t)b * 4096;
  for (int n = tid; n < 4096; n += TPB) S[SW(n)] = xb[n];
  for (int n = 4096 + tid; n < 8192; n += TPB) S[n] = make_float2(0.f, 0.f);
  __syncthreads();
  dif8_stage<8192,TPB>(S, 8192, tid); __syncthreads();
  dif8_stage<8192,TPB>(S, 1024, tid); __syncthreads();
  dif8_stage<8192,TPB>(S, 128, tid);  __syncthreads();
  dif8_stage<8192,TPB>(S, 16, tid);   __syncthreads();
  r2_stage<8192,TPB>(S, tid);         __syncthreads();
  for (int m = tid; m < 4097; m += TPB){
    int s, k;
    if (m == 4096){ s = 1; k = 4096; }
    else          { s = 2*m; k = siginv_even(m); }
    int j = (8192 - k) & 8191;
    int sj = sig8192(j);
    int as = SW(s), aj = SW(sj);
    float2 Zk = S[as], Zj = S[aj];
    float2 A  = make_float2(0.5f*(Zk.x + Zj.x), 0.5f*(Zk.y - Zj.y));
    float2 Bc = make_float2(0.5f*(Zk.x - Zj.x), 0.5f*(Zk.y + Zj.y));
    float sn, cn; __sincosf(-3.834951969714103e-4f * (float)k, &sn, &cn);
    float2 tb  = cmulf(make_float2(cn, sn), Bc);
    float2 tcb = cmulf(make_float2(cn, -sn), make_float2(Bc.x, -Bc.y));
    float2 Xk = make_float2(A.x + tb.y,  A.y - tb.x);
    float2 Xm = make_float2(A.x + tcb.y, -A.y - tcb.x);
    float2 Yk = cmulf(Xk, Ta[m]);
    float2 Ym = cmulf(Xm, Tb[m]);
    float2 E = make_float2(0.5f*(Yk.x + Ym.x), 0.5f*(Yk.y - Ym.y));
    float2 D = make_float2(0.5f*(Yk.x - Ym.x), 0.5f*(Yk.y + Ym.y));
    float2 Od = cmulf(make_float2(cn, -sn), D);
    S[as] = make_float2(E.x - Od.y, E.y + Od.x);
    if (aj != as)
      S[aj] = make_float2(E.x + Od.y, Od.x - E.y);
  }
  __syncthreads();
  r2_stage<8192,TPB>(S, tid);         __syncthreads();
  dit8_stage<8192,TPB>(S, 16, tid);   __syncthreads();
  dit8_stage<8192,TPB>(S, 128, tid);  __syncthreads();
  dit8_stage<8192,TPB>(S, 1024, tid); __syncthreads();
  dit8_stage<8192,TPB>(S, 8192, tid); __syncthreads();
  float2* yb = y2 + (size_t)b * 4096;
  for (int n = tid; n < 4096; n += TPB) yb[n] = S[SW(n)];
}

extern "C" void kernel_launch(void* const* d_in, const int* in_sizes, int n_in,
                              void* d_out, int out_size, void* d_ws, size_t ws_size,
                              hipStream_t stream){
  (void)n_in; (void)out_size; (void)ws_size;
  const float* x  = (const float*)d_in[0];
  const float* Bp = (const float*)d_in[1];
  const float* Cp = (const float*)d_in[2];
  // ws: Y[8192] double2 @0 (128K), T[8192] double @131072 (64K),
  //     Ta[4097] float2 @196608, Tb[4097] float2 @229632  (~257 KB)
  double2* Yt = (double2*)d_ws;
  double*  Tt = (double*)((char*)d_ws + 131072);
  float2*  Ta = (float2*)((char*)d_ws + 196608);
  float2*  Tb = (float2*)((char*)d_ws + 229632);
  const int batch = in_sizes[0] / 8192;
  hipLaunchKernelGGL(s4_khat_kernel, dim3(KHAT_CAUCHY_WGS + 32), dim3(256), 0, stream,
                     Bp, Cp, Yt, Tt);
  hipLaunchKernelGGL(s4_tabs_kernel, dim3(512), dim3(256), 0, stream, Yt, Tt, Ta, Tb);
  hipLaunchKernelGGL(s4_conv_kernel, dim3(batch), dim3(TPB), 0, stream,
                     (const float2*)x, (const float2*)Ta, (const float2*)Tb, (float2*)d_out);
}

// Round 7
// 153.232 us; speedup vs baseline: 1.2094x; 1.0326x over previous
//
#include <hip/hip_runtime.h>
#include <math.h>

// S4 DPLR kernel + batched causal convolution via custom packed-real FFTs.
//
//  A) s4_khat_kernel : wave-per-l Cauchy sum (byte-identical to r6, verified).
//  B) s4_tabs_kernel : LDS-staged Dirichlet odd bins + S_K + sigma-permuted
//       pair tables (byte-identical to r5/r6, verified).
//  C) s4_conv_kernel v2 : per batch (1024 WGs, 512 thr, 64KB LDS):
//       pack(lower half only) -> dif8_first (upper-half-zero specialized)
//       -> dif8(1024) -> dif8(128) -> fwd_tail16 (dif8(16)+r2 merged in regs,
//       W16 twiddles as constants) -> pointwise pair loop (unchanged)
//       -> inv_head16 (r2+dit8(16) merged) -> dit8(128) -> dit8(1024)
//       -> dit8_last (writes lower half only) -> store.
//       Same math as r2-r6 conv (sigma order and pointwise untouched);
//       removes 2 full LDS passes + zero-fill + 2 barriers (~23% LDS ops).
//
// LDS addresses go through SW(x) = x ^ ((x>>4)&15) to kill bank conflicts.
// SW permutes only within aligned 16-blocks: SW(16v+o) = 16v + (o^(v&15)),
// which is what makes the in-register radix-16 tail own one contiguous block.

#define TPB 512

__device__ __forceinline__ int SW(int x){ return x ^ ((x >> 4) & 15); }

__device__ __forceinline__ float2 cadd(float2 a, float2 b){ return make_float2(a.x+b.x, a.y+b.y); }
__device__ __forceinline__ float2 csub(float2 a, float2 b){ return make_float2(a.x-b.x, a.y-b.y); }
__device__ __forceinline__ float2 cmulf(float2 a, float2 b){
  return make_float2(a.x*b.x - a.y*b.y, a.x*b.y + a.y*b.x);
}
__device__ __forceinline__ float2 cmulcf(float2 a, float2 b){  // a * conj(b)
  return make_float2(a.x*b.x + a.y*b.y, a.y*b.x - a.x*b.y);
}
template<int SGN>
__device__ __forceinline__ float2 muli(float2 v){
  return (SGN > 0) ? make_float2(-v.y, v.x) : make_float2(v.y, -v.x);
}

template<int SGN>   // -1: forward DFT8; +1: conj (unscaled inverse)
__device__ __forceinline__ void dft8(const float2* a, float2* X){
  const float C  = 0.70710678118654752f;
  const float SC = (SGN > 0) ? C : -C;
  float2 e0=cadd(a[0],a[4]), e1=csub(a[0],a[4]);
  float2 e2=cadd(a[2],a[6]), e3=csub(a[2],a[6]);
  float2 f0=cadd(a[1],a[5]), f1=csub(a[1],a[5]);
  float2 f2=cadd(a[3],a[7]), f3=csub(a[3],a[7]);
  float2 ie3 = muli<SGN>(e3), if3 = muli<SGN>(f3);
  float2 E0=cadd(e0,e2), E2=csub(e0,e2);
  float2 E1=cadd(e1,ie3), E3=csub(e1,ie3);
  float2 O0=cadd(f0,f2), O2=csub(f0,f2);
  float2 O1=cadd(f1,if3), O3=csub(f1,if3);
  float2 O2r = muli<SGN>(O2);
  float2 O1r = cmulf(O1, make_float2(C,  SC));
  float2 O3r = cmulf(O3, make_float2(-C, SC));
  X[0]=cadd(E0,O0);  X[4]=csub(E0,O0);
  X[1]=cadd(E1,O1r); X[5]=csub(E1,O1r);
  X[2]=cadd(E2,O2r); X[6]=csub(E2,O2r);
  X[3]=cadd(E3,O3r); X[7]=csub(E3,O3r);
}

// W16^q = e^{-2pi i q/16}, q=0..7 (forward DIF twiddles of the size-16 stage)
__device__ __forceinline__ void w16_tab(float2* W){
  W[0] = make_float2( 1.f, 0.f);
  W[1] = make_float2( 0.923879533f, -0.382683432f);
  W[2] = make_float2( 0.707106781f, -0.707106781f);
  W[3] = make_float2( 0.382683432f, -0.923879533f);
  W[4] = make_float2( 0.f, -1.f);
  W[5] = make_float2(-0.382683432f, -0.923879533f);
  W[6] = make_float2(-0.707106781f, -0.707106781f);
  W[7] = make_float2(-0.923879533f, -0.382683432f);
}

template<int NFFT, int T>
__device__ void dif8_stage(float2* S, int size, int tid){
  const int t = size >> 3;
  const float ang = -6.283185307179586f / (float)size;
  for (int u = tid; u < (NFFT >> 3); u += T){
    int j = u & (t - 1);
    int base = ((u - j) << 3) + j;
    float2 a[8], X[8];
#pragma unroll
    for (int q = 0; q < 8; q++) a[q] = S[SW(base + q*t)];
    dft8<-1>(a, X);
    if (t > 1){
      float sn, cn; __sincosf(ang * (float)j, &sn, &cn);
      float2 w = make_float2(cn, sn), wq = w;
#pragma unroll
      for (int q = 1; q < 8; q++){ X[q] = cmulf(X[q], wq); wq = cmulf(wq, w); }
    }
#pragma unroll
    for (int q = 0; q < 8; q++) S[SW(base + q*t)] = X[q];
  }
}

// first forward stage (size = NFFT): inputs at q>=4 are the zero padding —
// never read them (zero-fill pass deleted); compiler folds the zero adds.
template<int NFFT, int T>
__device__ void dif8_first(float2* S, int tid){
  const int t = NFFT >> 3;
  const float ang = -6.283185307179586f / (float)NFFT;
  for (int u = tid; u < (NFFT >> 3); u += T){
    int j = u & (t - 1);
    int base = ((u - j) << 3) + j;
    float2 a[8], X[8];
#pragma unroll
    for (int q = 0; q < 4; q++) a[q] = S[SW(base + q*t)];
#pragma unroll
    for (int q = 4; q < 8; q++) a[q] = make_float2(0.f, 0.f);
    dft8<-1>(a, X);
    float sn, cn; __sincosf(ang * (float)j, &sn, &cn);
    float2 w = make_float2(cn, sn), wq = w;
#pragma unroll
    for (int q = 1; q < 8; q++){ X[q] = cmulf(X[q], wq); wq = cmulf(wq, w); }
#pragma unroll
    for (int q = 0; q < 8; q++) S[SW(base + q*t)] = X[q];
  }
}

template<int NFFT, int T>
__device__ void dit8_stage(float2* S, int size, int tid){
  const int t = size >> 3;
  const float ang = 6.283185307179586f / (float)size;
  for (int u = tid; u < (NFFT >> 3); u += T){
    int j = u & (t - 1);
    int base = ((u - j) << 3) + j;
    float2 a[8], X[8];
#pragma unroll
    for (int q = 0; q < 8; q++) a[q] = S[SW(base + q*t)];
    if (t > 1){
      float sn, cn; __sincosf(ang * (float)j, &sn, &cn);
      float2 w = make_float2(cn, sn), wq = w;
#pragma unroll
      for (int q = 1; q < 8; q++){ a[q] = cmulf(a[q], wq); wq = cmulf(wq, w); }
    }
    dft8<1>(a, X);
#pragma unroll
    for (int q = 0; q < 8; q++) S[SW(base + q*t)] = X[q];
  }
}

// last inverse stage (size = NFFT): only outputs q<4 (addresses < NFFT/2) are
// ever read afterwards (packed irfft uses the lower half) — skip upper writes.
template<int NFFT, int T>
__device__ void dit8_last(float2* S, int tid){
  const int t = NFFT >> 3;
  const float ang = 6.283185307179586f / (float)NFFT;
  for (int u = tid; u < (NFFT >> 3); u += T){
    int j = u & (t - 1);
    int base = ((u - j) << 3) + j;
    float2 a[8], X[8];
#pragma unroll
    for (int q = 0; q < 8; q++) a[q] = S[SW(base + q*t)];
    float sn, cn; __sincosf(ang * (float)j, &sn, &cn);
    float2 w = make_float2(cn, sn), wq = w;
#pragma unroll
    for (int q = 1; q < 8; q++){ a[q] = cmulf(a[q], wq); wq = cmulf(wq, w); }
    dft8<1>(a, X);
#pragma unroll
    for (int q = 0; q < 4; q++) S[SW(base + q*t)] = X[q];
  }
}

// merged dif8(size=16) + r2: thread v owns block [16v,16v+16); j=0 butterflies
// on even offsets, j=1 on odds with constant W16 twiddles, then the 8 r2 pairs
// — all in registers. Bit-compatible with the two separate passes of r2-r6.
template<int T>
__device__ void fwd_tail16(float2* S, int tid){
  float2 W[8]; w16_tab(W);
  for (int v = tid; v < 512; v += T){
    const int base = v << 4;
    const int sw = v & 15;
    float2 a0[8], a1[8], X0[8], X1[8];
#pragma unroll
    for (int q = 0; q < 8; q++){
      a0[q] = S[base + ((2*q)     ^ sw)];
      a1[q] = S[base + ((2*q + 1) ^ sw)];
    }
    dft8<-1>(a0, X0);
    dft8<-1>(a1, X1);
#pragma unroll
    for (int q = 0; q < 8; q++){
      float2 tq = cmulf(X1[q], W[q]);                 // j=1 twiddle (const)
      S[base + ((2*q)     ^ sw)] = cadd(X0[q], tq);   // r2 sum
      S[base + ((2*q + 1) ^ sw)] = csub(X0[q], tq);   // r2 diff
    }
  }
}

// merged r2 + dit8(size=16): r2 pairs in registers, then the two inverse
// size-16 butterflies (j=1 inputs get conj(W16) twiddles).
template<int T>
__device__ void inv_head16(float2* S, int tid){
  float2 W[8]; w16_tab(W);
  for (int v = tid; v < 512; v += T){
    const int base = v << 4;
    const int sw = v & 15;
    float2 p0[8], p1[8], X0[8], X1[8];
#pragma unroll
    for (int q = 0; q < 8; q++){
      float2 e = S[base + ((2*q)     ^ sw)];
      float2 o = S[base + ((2*q + 1) ^ sw)];
      p0[q] = cadd(e, o);                 // r2 -> even offsets (j=0 inputs)
      p1[q] = cmulcf(csub(e, o), W[q]);   // r2 diff * conj(W16^q) (j=1 inputs)
    }
    dft8<1>(p0, X0);
    dft8<1>(p1, X1);
#pragma unroll
    for (int q = 0; q < 8; q++){
      S[base + ((2*q)     ^ sw)] = X0[q];   // j=0 outputs at even offsets
      S[base + ((2*q + 1) ^ sw)] = X1[q];   // j=1 outputs at odd offsets
    }
  }
}

__device__ __forceinline__ int sig8192(int k){
  return ((k & 7) << 10) | (((k >> 3) & 7) << 7) | (((k >> 6) & 7) << 4)
       | (((k >> 9) & 7) << 1) | ((k >> 12) & 1);
}
__device__ __forceinline__ int siginv_even(int m){  // k such that sig8192(k) == 2m
  return (m >> 9) | (((m >> 6) & 7) << 3) | (((m >> 3) & 7) << 6) | ((m & 7) << 9);
}

__device__ __forceinline__ double wsum64(double v){
#pragma unroll
  for (int m = 32; m > 0; m >>= 1) v += __shfl_xor(v, m, 64);
  return v;
}

// A) wave-per-l Cauchy (fp64) -> Hermitian-forced Y[0..8191]; T via WGs>=1025
#define KHAT_CAUCHY_WGS 1025
__global__ __launch_bounds__(256) void s4_khat_kernel(const float* __restrict__ Bp,
                                                      const float* __restrict__ Cp,
                                                      double2* __restrict__ Y,
                                                      double* __restrict__ T){
  const double PI = 3.14159265358979323846264338327950288;
  const int bid = blockIdx.x;
  const int tid = threadIdx.x;
  if (bid >= KHAT_CAUCHY_WGS){
    int d = (bid - KHAT_CAUCHY_WGS) * 256 + tid;
    double phi = PI * (double)(2*d - 1) / 16384.0;
    double s, c; sincos(phi, &s, &c);
    T[d] = c / s;
    return;
  }
  const int l = bid * 4 + (tid >> 6);     // one wave per bin l
  const int n = tid & 63;                 // lane owns pole n
  if (l > 4096) return;
  double th = (2.0 * PI / 8192.0) * (double)l;
  double wr = cos(th), wi = sin(th);
  double ux = 1.0 + wr, uy = wi;
  double vx = 1.0 - wr, vy = -wi;
  double gx = 20.0 * vx, gy = 20.0 * vy;
  double Bn = (double)Bp[n], Cn = (double)Cp[n];
  double Pn = sqrt((double)n + 0.5);
  double lx = -0.5, ly = PI * (double)n;
  double dx = gx - (ux*lx - uy*ly);
  double dy = gy - (ux*ly + uy*lx);
  double inv2 = 2.0 / (dx*dx + dy*dy);
  double cix = dx * inv2, ciy = -dy * inv2;
  double w00 = Cn*Bn, w01 = Cn*Pn, w10 = Pn*Bn, w11 = Pn*Pn;
  double s00x = wsum64(w00*cix), s00y = wsum64(w00*ciy);
  double s01x = wsum64(w01*cix), s01y = wsum64(w01*ciy);
  double s10x = wsum64(w10*cix), s10y = wsum64(w10*ciy);
  double s11x = wsum64(w11*cix), s11y = wsum64(w11*ciy);
  double hux = 0.5*ux, huy = 0.5*uy;
  double k11x = hux*s11x - huy*s11y;
  double k11y = hux*s11y + huy*s11x;
  double p1x = 1.0 + k11x, p1y = k11y;
  double t1x = s01x*p1x - s01y*p1y, t1y = s01x*p1y + s01y*p1x;
  double t2x = t1x*s10x - t1y*s10y, t2y = t1x*s10y + t1y*s10x;
  double crx = t2x*hux - t2y*huy,   cry = t2x*huy + t2y*hux;
  double vr = s00x - crx, vi = s00y - cry;
  if (n == 0){
    if (l == 0 || l == 4096) Y[l] = make_double2(vr, 0.0);
    else                     Y[l] = make_double2(vr, vi);
  } else if (n == 1 && l != 0 && l != 4096){
    Y[8192 - l] = make_double2(vr, -vi);
  }
}

// B) LDS-staged Dirichlet odd bins + S_K + table writes — byte-identical to r5/r6
__global__ __launch_bounds__(256) void s4_tabs_kernel(const double2* __restrict__ Y,
                                                      const double* __restrict__ T,
                                                      float2* __restrict__ Ta,
                                                      float2* __restrict__ Tb){
  __shared__ __align__(16) float2 Ys[8192];
  const int tid = threadIdx.x;
  const int g   = blockIdx.x;        // 0..511
  const int lA  = g * 4;
  const int lB  = 4092 - lA;
  double skr = 0.0, ski = 0.0;
  for (int m = tid; m < 8192; m += 256){
    double2 v = Y[m];
    skr += v.x; ski += v.y;
    Ys[m] = make_float2((float)v.x, (float)v.y);
  }
  __syncthreads();
  double aAr[4]={0,0,0,0}, aAi[4]={0,0,0,0};
  double aBr[4]={0,0,0,0}, aBi[4]={0,0,0,0};
#pragma unroll 4
  for (int s = 0; s < 32; s++){
    const int d = (s << 8) + tid;
    const double t = T[d];
#pragma unroll
    for (int j = 0; j < 4; j++){
      float2 va = Ys[(lA + j + d) & 8191];
      float2 vb = Ys[(lB + j + d) & 8191];
      aAr[j] += t * (double)va.x;  aAi[j] += t * (double)va.y;
      aBr[j] += t * (double)vb.x;  aBi[j] += t * (double)vb.y;
    }
  }
  __syncthreads();
  double2 (*red)[9] = (double2 (*)[9])(void*)Ys;
#pragma unroll
  for (int j = 0; j < 4; j++){
    red[tid][j]     = make_double2(aAr[j], aAi[j]);
    red[tid][4 + j] = make_double2(aBr[j], aBi[j]);
  }
  red[tid][8] = make_double2(skr, ski);
  __syncthreads();
  for (int h = 128; h > 0; h >>= 1){
    if (tid < h){
#pragma unroll
      for (int j = 0; j < 9; j++){
        red[tid][j].x += red[tid + h][j].x;
        red[tid][j].y += red[tid + h][j].y;
      }
    }
    __syncthreads();
  }
  if (tid < 4){
    const int l = lA + tid;
    const double SKr = red[0][8].x, SKi = red[0][8].y;
    const double Por = red[0][tid].x, Poi = red[0][tid].y;
    const double Pmr = red[0][4 + (3 - tid)].x, Pmi = red[0][4 + (3 - tid)].y;
    const double q = (1.0/8192.0) * (1.0/8192.0);
    int mo = sig8192(2*l + 1) >> 1;
    Ta[mo] = make_float2((float)((SKr - Poi) * q), (float)((SKi + Por) * q));
    Tb[mo] = make_float2((float)((SKr - Pmi) * q), (float)((SKi + Pmr) * q));
    const double sc = 1.0/8192.0;
    int me = sig8192(2*l) >> 1;
    double2 ye = Y[l];
    double2 yo = Y[4096 - l];
    Ta[me] = make_float2((float)(ye.x * sc), (float)(ye.y * sc));
    Tb[me] = make_float2((float)(yo.x * sc), (float)(yo.y * sc));
  }
  if (g == 0 && tid == 4){
    double2 yn = Y[2048];
    float2 v = make_float2((float)(yn.x / 8192.0), (float)(yn.y / 8192.0));
    Ta[4096] = v; Tb[4096] = v;
  }
}

// C) conv v2 — merged tails, zero-pad specialization; sigma/pointwise unchanged
__global__ __launch_bounds__(TPB, 4) void s4_conv_kernel(const float2* __restrict__ x2,
                                                         const float2* __restrict__ Ta,
                                                         const float2* __restrict__ Tb,
                                                         float2* __restrict__ y2){
  __shared__ __align__(16) float2 S[8192];
  const int tid = threadIdx.x;
  const int b = blockIdx.x;
  const float2* xb = x2 + (size_t)b * 4096;
  for (int n = tid; n < 4096; n += TPB) S[SW(n)] = xb[n];
  // (no zero-fill: dif8_first never reads the upper half)
  __syncthreads();
  dif8_first<8192,TPB>(S, tid);       __syncthreads();
  dif8_stage<8192,TPB>(S, 1024, tid); __syncthreads();
  dif8_stage<8192,TPB>(S, 128, tid);  __syncthreads();
  fwd_tail16<TPB>(S, tid);            __syncthreads();
  for (int m = tid; m < 4097; m += TPB){
    int s, k;
    if (m == 4096){ s = 1; k = 4096; }
    else          { s = 2*m; k = siginv_even(m); }
    int j = (8192 - k) & 8191;
    int sj = sig8192(j);
    int as = SW(s), aj = SW(sj);
    float2 Zk = S[as], Zj = S[aj];
    float2 A  = make_float2(0.5f*(Zk.x + Zj.x), 0.5f*(Zk.y - Zj.y));
    float2 Bc = make_float2(0.5f*(Zk.x - Zj.x), 0.5f*(Zk.y + Zj.y));
    float sn, cn; __sincosf(-3.834951969714103e-4f * (float)k, &sn, &cn);
    float2 tb  = cmulf(make_float2(cn, sn), Bc);
    float2 tcb = cmulf(make_float2(cn, -sn), make_float2(Bc.x, -Bc.y));
    float2 Xk = make_float2(A.x + tb.y,  A.y - tb.x);
    float2 Xm = make_float2(A.x + tcb.y, -A.y - tcb.x);
    float2 Yk = cmulf(Xk, Ta[m]);
    float2 Ym = cmulf(Xm, Tb[m]);
    float2 E = make_float2(0.5f*(Yk.x + Ym.x), 0.5f*(Yk.y - Ym.y));
    float2 D = make_float2(0.5f*(Yk.x - Ym.x), 0.5f*(Yk.y + Ym.y));
    float2 Od = cmulf(make_float2(cn, -sn), D);
    S[as] = make_float2(E.x - Od.y, E.y + Od.x);
    if (aj != as)
      S[aj] = make_float2(E.x + Od.y, Od.x - E.y);
  }
  __syncthreads();
  inv_head16<TPB>(S, tid);            __syncthreads();
  dit8_stage<8192,TPB>(S, 128, tid);  __syncthreads();
  dit8_stage<8192,TPB>(S, 1024, tid); __syncthreads();
  dit8_last<8192,TPB>(S, tid);        __syncthreads();
  float2* yb = y2 + (size_t)b * 4096;
  for (int n = tid; n < 4096; n += TPB) yb[n] = S[SW(n)];
}

extern "C" void kernel_launch(void* const* d_in, const int* in_sizes, int n_in,
                              void* d_out, int out_size, void* d_ws, size_t ws_size,
                              hipStream_t stream){
  (void)n_in; (void)out_size; (void)ws_size;
  const float* x  = (const float*)d_in[0];
  const float* Bp = (const float*)d_in[1];
  const float* Cp = (const float*)d_in[2];
  // ws: Y[8192] double2 @0 (128K), T[8192] double @131072 (64K),
  //     Ta[4097] float2 @196608, Tb[4097] float2 @229632  (~257 KB)
  double2* Yt = (double2*)d_ws;
  double*  Tt = (double*)((char*)d_ws + 131072);
  float2*  Ta = (float2*)((char*)d_ws + 196608);
  float2*  Tb = (float2*)((char*)d_ws + 229632);
  const int batch = in_sizes[0] / 8192;
  hipLaunchKernelGGL(s4_khat_kernel, dim3(KHAT_CAUCHY_WGS + 32), dim3(256), 0, stream,
                     Bp, Cp, Yt, Tt);
  hipLaunchKernelGGL(s4_tabs_kernel, dim3(512), dim3(256), 0, stream, Yt, Tt, Ta, Tb);
  hipLaunchKernelGGL(s4_conv_kernel, dim3(batch), dim3(TPB), 0, stream,
                     (const float2*)x, (const float2*)Ta, (const float2*)Tb, (float2*)d_out);
}